// Round 13
// baseline (133.820 us; speedup 1.0000x reference)
//
#include <hip/hip_runtime.h>
#include <hip/hip_bf16.h>
#include <math.h>

// Problem constants (fixed by setup_inputs)
#define NB   8          // batch
#define NS   1024       // seq len
#define NDM  512        // d_model
#define NH   8          // heads
#define NDK  64         // d_k
#define NM   8192       // NB*NS

typedef __attribute__((ext_vector_type(8))) short short8;
typedef __attribute__((ext_vector_type(4))) float f32x4;

// truncation f32->bf16 (1 VALU op/elem; error <= 2^-8 relative vs RNE 2^-9 —
// within this problem's 4.8x absmax headroom)
__device__ __forceinline__ unsigned int pack2t(float lo, float hi) {
    return (__float_as_uint(hi) & 0xffff0000u) | (__float_as_uint(lo) >> 16);
}
__device__ __forceinline__ unsigned short f2bt(float f) {
    return (unsigned short)(__float_as_uint(f) >> 16);
}
__device__ __forceinline__ float b2f(unsigned short u) {
    return __uint_as_float(((unsigned)u) << 16);
}
// raw transcendentals (v_exp_f32 is natively 2^x)
__device__ __forceinline__ float exp2_raw(float x) { float r; asm("v_exp_f32 %0, %1" : "=v"(r) : "v"(x)); return r; }
__device__ __forceinline__ float sqrt_raw(float x) { float r; asm("v_sqrt_f32 %0, %1" : "=v"(r) : "v"(x)); return r; }
__device__ __forceinline__ float rcp_raw(float x)  { float r; asm("v_rcp_f32 %0, %1" : "=v"(r) : "v"(x)); return r; }

// DPP helpers (cross-lane at VALU rate)
template<int CTRL, int RM>
__device__ __forceinline__ float dpp_mov0(float x) {
    int m = __builtin_amdgcn_update_dpp(0, __float_as_int(x), CTRL, RM, 0xf, true);
    return __int_as_float(m);
}
__device__ __forceinline__ float wave_incl_scan(float x) {
    x += dpp_mov0<0x111, 0xf>(x);   // row_shr:1
    x += dpp_mov0<0x112, 0xf>(x);   // row_shr:2
    x += dpp_mov0<0x114, 0xf>(x);   // row_shr:4
    x += dpp_mov0<0x118, 0xf>(x);   // row_shr:8
    x += dpp_mov0<0x142, 0xa>(x);   // row_bcast:15 -> rows 1,3
    x += dpp_mov0<0x143, 0xc>(x);   // row_bcast:31 -> rows 2,3
    return x;
}
__device__ __forceinline__ float lane63(float x) {
    return __int_as_float(__builtin_amdgcn_readlane(__float_as_int(x), 63));
}

// trunc-pack 8 consecutive f32 -> 8 bf16 (4 uint)
__device__ __forceinline__ uint4 pack8t(const float* p) {
    const unsigned int* u = (const unsigned int*)p;
    uint4 a = *(const uint4*)u;
    uint4 b = *(const uint4*)(u + 4);
    uint4 r;
    r.x = (a.y & 0xffff0000u) | (a.x >> 16);
    r.y = (a.w & 0xffff0000u) | (a.z >> 16);
    r.z = (b.y & 0xffff0000u) | (b.x >> 16);
    r.w = (b.w & 0xffff0000u) | (b.z >> 16);
    return r;
}

// async 16B global -> LDS (wave-uniform dest base + lane*16; per-lane SOURCE ok)
__device__ __forceinline__ void gload16(const unsigned short* g, unsigned short* l) {
    __builtin_amdgcn_global_load_lds(
        (const __attribute__((address_space(1))) void*)g,
        (__attribute__((address_space(3))) void*)l, 16, 0, 0);
}

// C = A @ W^T + bias.  BM=128, BN=128, BK=64 (m97 geometry: 32 MFMA/wave/k-step).
// XOR-swizzled LDS (chunk ^= row&7), conflict-free b128 reads; DMA path
// pre-swizzles the GLOBAL source (LDS dest linear — G21 both-sides rule).
// ACVT/BCVT: f32 source -> trunc-convert in staging; else bf16 DMA.
// OMODE 0: out bf16 [b][h][s][d]; 1: bf16 [b][h][d][s]; 2: f32 [m][n].
template<int OMODE, bool ACVT, bool BCVT>
__device__ __forceinline__ void gemm_body128(unsigned short* As, unsigned short* Bs,
                                             const void* __restrict__ Ap,
                                             const void* __restrict__ Wp,
                                             const float* __restrict__ bias,
                                             void* __restrict__ outp) {
    const int tid = threadIdx.x, lane = tid & 63, wid = tid >> 6;
    const int l15 = lane & 15, lhi = lane >> 4;
    const int m0 = (blockIdx.x >> 2) * 128;   // 64 M-tiles
    const int n0 = (blockIdx.x & 3) * 128;    // 4 N-tiles
    const int wr = wid >> 1, wc = wid & 1;    // wave -> 64x64 output quadrant
    const float* Af = (const float*)Ap;
    const unsigned short* Ab = (const unsigned short*)Ap;
    const float* Wf = (const float*)Wp;
    const unsigned short* Wb = (const unsigned short*)Wp;

    f32x4 acc[4][4];
#pragma unroll
    for (int i = 0; i < 4; ++i)
#pragma unroll
        for (int j = 0; j < 4; ++j) acc[i][j] = (f32x4){0.f, 0.f, 0.f, 0.f};

    for (int kk0 = 0; kk0 < NDM; kk0 += 64) {
        // ---- stage A: 128 rows x 64 k (16 KB bf16), 1024 16B-chunks ----
#pragma unroll
        for (int c = 0; c < 4; ++c) {
            int ci = tid + 256 * c, row = ci >> 3, ch = ci & 7;
            int sch = ch ^ (row & 7);
            if (ACVT) {
                const float* p = Af + (size_t)(m0 + row) * NDM + kk0 + ch * 8;
                *(uint4*)(As + row * 64 + sch * 8) = pack8t(p);
            } else {
                gload16(Ab + (size_t)(m0 + row) * NDM + kk0 + sch * 8, As + ci * 8);
            }
        }
        // ---- stage B: 128 rows x 64 k (16 KB bf16) ----
#pragma unroll
        for (int c = 0; c < 4; ++c) {
            int ci = tid + 256 * c, row = ci >> 3, ch = ci & 7;
            int sch = ch ^ (row & 7);
            if (BCVT) {
                const float* p = Wf + (size_t)(n0 + row) * NDM + kk0 + ch * 8;
                *(uint4*)(Bs + row * 64 + sch * 8) = pack8t(p);
            } else {
                gload16(Wb + (size_t)(n0 + row) * NDM + kk0 + sch * 8, Bs + ci * 8);
            }
        }
        __syncthreads();
        // kk-inner keeps fragment liveness low (8 short8 live, not 16)
#pragma unroll
        for (int kk = 0; kk < 2; ++kk) {
            short8 af[4], bf[4];
#pragma unroll
            for (int mi = 0; mi < 4; ++mi) {
                int row = wr * 64 + mi * 16 + l15;
                af[mi] = *(const short8*)(As + row * 64 + (((kk * 4 + lhi) ^ (l15 & 7)) << 3));
            }
#pragma unroll
            for (int ni = 0; ni < 4; ++ni) {
                int row = wc * 64 + ni * 16 + l15;
                bf[ni] = *(const short8*)(Bs + row * 64 + (((kk * 4 + lhi) ^ (l15 & 7)) << 3));
            }
#pragma unroll
            for (int mi = 0; mi < 4; ++mi)
#pragma unroll
                for (int ni = 0; ni < 4; ++ni)
                    acc[mi][ni] = __builtin_amdgcn_mfma_f32_16x16x32_bf16(af[mi], bf[ni], acc[mi][ni], 0, 0, 0);
        }
        __syncthreads();
    }

#pragma unroll
    for (int mi = 0; mi < 4; ++mi) {
#pragma unroll
        for (int ni = 0; ni < 4; ++ni) {
            int row0 = m0 + wr * 64 + mi * 16 + lhi * 4;
            int col  = n0 + wc * 64 + ni * 16 + l15;
            float bv = bias[col];
            if (OMODE == 0) {
                unsigned short* o = (unsigned short*)outp;
                int h = col >> 6, d = col & 63;
#pragma unroll
                for (int r = 0; r < 4; ++r) {
                    int m = row0 + r;
                    int b = m >> 10, s = m & 1023;
                    o[(size_t)(((b * NH + h) * NS) + s) * NDK + d] = f2bt(acc[mi][ni][r] + bv);
                }
            } else if (OMODE == 1) {
                unsigned short* o = (unsigned short*)outp;
                int h = col >> 6, d = col & 63;
                int b = row0 >> 10, s0 = row0 & 1023;
                uint2 pu;
                pu.x = pack2t(acc[mi][ni][0] + bv, acc[mi][ni][1] + bv);
                pu.y = pack2t(acc[mi][ni][2] + bv, acc[mi][ni][3] + bv);
                *(uint2*)(o + (size_t)((b * NH + h) * NDK + d) * NS + s0) = pu;
            } else {
                float* o = (float*)outp;
#pragma unroll
                for (int r = 0; r < 4; ++r)
                    o[(size_t)(row0 + r) * NDM + col] = acc[mi][ni][r] + bv;
            }
        }
    }
}

// QKV projections: grid (256, 3); A f32 + W f32 trunc-convert in staging.
__global__ __launch_bounds__(256) void qkv_gemm(const float* __restrict__ q,
                                                const float* __restrict__ k,
                                                const float* __restrict__ v,
                                                const float* __restrict__ Wq,
                                                const float* __restrict__ Wk,
                                                const float* __restrict__ Wv,
                                                const float* __restrict__ bq,
                                                const float* __restrict__ bk,
                                                const float* __restrict__ bv,
                                                unsigned short* __restrict__ Qh,
                                                unsigned short* __restrict__ Kh,
                                                unsigned short* __restrict__ Vt) {
    __shared__ unsigned short As[128 * 64];
    __shared__ unsigned short Bs[128 * 64];
    const int y = blockIdx.y;
    if (y == 0)      gemm_body128<0, true, true>(As, Bs, q, Wq, bq, Qh);
    else if (y == 1) gemm_body128<0, true, true>(As, Bs, k, Wk, bk, Kh);
    else             gemm_body128<1, true, true>(As, Bs, v, Wv, bv, Vt);
}

// Wo GEMM: A (concat bf16) via DMA w/ pre-swizzled source, Wo f32 trunc-staged.
__global__ __launch_bounds__(256) void wo_gemm(const unsigned short* __restrict__ A,
                                               const float* __restrict__ Wo,
                                               const float* __restrict__ bo,
                                               float* __restrict__ out) {
    __shared__ unsigned short As[128 * 64];
    __shared__ unsigned short Bs[128 * 64];
    gemm_body128<2, false, true>(As, Bs, A, Wo, bo, out);
}

// Phase-2 row processor: EW = cols per lane (8 for C<=512 tiles, 16 otherwise).
template<int EW>
__device__ __forceinline__ void phase2_rows(unsigned short* pb, int r0, int wid,
                                            int lane, float g2) {
    const int cb = lane * EW;
#pragma unroll
    for (int t = 0; t < 4; ++t) {
        const int rr = wid + 4 * t;
        const int i  = r0 + rr;
        unsigned short* rowp = pb + rr * 1024;
        float s[EW];
        if (EW == 8) {
            short8 raw = *(const short8*)(rowp + ((lane ^ rr) << 3));
#pragma unroll
            for (int u = 0; u < 8; ++u) s[u] = b2f((unsigned short)raw[u]);
        } else {
            short8 raw0 = *(const short8*)(rowp + (((2 * lane)     ^ rr) << 3));
            short8 raw1 = *(const short8*)(rowp + (((2 * lane + 1) ^ rr) << 3));
#pragma unroll
            for (int u = 0; u < 8; ++u) {
                s[u]     = b2f((unsigned short)raw0[u]);
                s[(EW == 16 ? 8 : 0) + u] = b2f((unsigned short)raw1[u]);
            }
        }
        // causal mask (also sanitizes stale cols beyond C: there cb+u >= C > i)
#pragma unroll
        for (int u = 0; u < EW; ++u)
            if (cb + u > i) s[u] = -1e30f;
        // softmax1 (no max): exp2 + local inclusive prefix
        float p[EW];
        float run = 0.f;
#pragma unroll
        for (int u = 0; u < EW; ++u) { run += exp2_raw(s[u]); p[u] = run; }
        const float inc      = wave_incl_scan(run);
        const float l1       = lane63(inc);
        const float invl1    = rcp_raw(l1);
        const float taillane = l1 - (inc - run);   // l1 - excl
        const float di       = (float)(i - cb);
        // decay + second softmax; masked cols: tail==0 -> te=1 -> w=0
        float l2 = 0.f;
#pragma unroll
        for (int u = 0; u < EW; ++u) {
            float tail = fmaxf(taillane - p[u], 0.f);
            float t2   = (tail * invl1) * (di - (float)u);
            float te   = fmaxf(exp2_raw(g2 * sqrt_raw(t2)), 1e-5f);
            float w    = exp2_raw(s[u] * te);
            s[u] = w;
            l2 += w;
        }
        const float l2t  = lane63(wave_incl_scan(l2));
        const float inv2 = rcp_raw(l2t);
        if (EW == 8) {
            uint4 h;
            h.x = pack2t(s[0] * inv2, s[1] * inv2);
            h.y = pack2t(s[2] * inv2, s[3] * inv2);
            h.z = pack2t(s[4] * inv2, s[5] * inv2);
            h.w = pack2t(s[6] * inv2, s[7] * inv2);
            *(uint4*)(rowp + ((lane ^ rr) << 3)) = h;
        } else {
            uint4 h0, h1;
            h0.x = pack2t(s[0] * inv2, s[1] * inv2);
            h0.y = pack2t(s[2] * inv2, s[3] * inv2);
            h0.z = pack2t(s[4] * inv2, s[5] * inv2);
            h0.w = pack2t(s[6] * inv2, s[7] * inv2);
            h1.x = pack2t(s[8] * inv2, s[9] * inv2);
            h1.y = pack2t(s[10] * inv2, s[11] * inv2);
            h1.z = pack2t(s[12] * inv2, s[13] * inv2);
            h1.w = pack2t(s[14] * inv2, s[15] * inv2);
            *(uint4*)(rowp + (((2 * lane)     ^ rr) << 3)) = h0;
            *(uint4*)(rowp + (((2 * lane + 1) ^ rr) << 3)) = h1;
        }
    }
}

// Fused causal attention with distance decay.  (R9/R12 memory structure.)
// bf16 LDS tile [16 rows][1024 cols] = 32768 B, 4 blocks/CU.
// Block = q-tile PAIR (p, 63-p); hs=0 -> EW=8 path.  bh in low 6 bits pins
// head to XCD bh%8 (K/V L2-resident, FETCH ~12 MB — do not perturb).
__global__ __launch_bounds__(256, 4) void attn_kernel(const unsigned short* __restrict__ Qh,
                                                      const unsigned short* __restrict__ Kh,
                                                      const unsigned short* __restrict__ Vt,
                                                      const float* __restrict__ gammas,
                                                      unsigned short* __restrict__ concat) {
    __shared__ unsigned short pb[16 * 1024];   // 32 KB bf16 tile (scores -> probs in place)
    const int bh   = blockIdx.x & 63;
    const int pair = blockIdx.x >> 6;          // 0..31
    const int tid = threadIdx.x, lane = tid & 63, wid = tid >> 6;
    const int l15 = lane & 15, lhi = lane >> 4;
    const float SC = 0.125f * 1.44269504f;     // score scale * log2(e)

    const unsigned short* Kb = Kh + (size_t)bh * NS * NDK;
    const unsigned short* Vb = Vt + (size_t)bh * NDK * NS;
    const float g  = gammas[bh & (NH - 1)];
    const float g2 = -log1pf(__expf(g)) * 1.44269504f;   // -softplus * log2(e)
    const int bq_ = bh >> 3, hq = bh & 7;

    for (int hs = 0; hs < 2; ++hs) {
        const int qt = hs ? (63 - pair) : pair;
        const int r0 = qt * 16;
        const int C  = ((r0 + 16 + 63) >> 6) << 6;   // cols computed (<=1024; <=512 for hs=0)

        // ---- Phase 1: swapped QK^T: D[k-local][q-local] = mfma(K_frag, Q_frag) ----
        const unsigned short* Qb = Qh + (size_t)(bh * NS + r0) * NDK;
        short8 qf0 = *(const short8*)(Qb + l15 * NDK + lhi * 8);
        short8 qf1 = *(const short8*)(Qb + l15 * NDK + lhi * 8 + 32);
        for (int j0 = wid * 16; j0 < C; j0 += 64) {
            const unsigned short* kp = Kb + (size_t)(j0 + l15) * NDK + lhi * 8;
            short8 kf0 = *(const short8*)kp;
            short8 kf1 = *(const short8*)(kp + 32);
            f32x4 a = {0.f, 0.f, 0.f, 0.f};
            a = __builtin_amdgcn_mfma_f32_16x16x32_bf16(kf0, qf0, a, 0, 0, 0);
            a = __builtin_amdgcn_mfma_f32_16x16x32_bf16(kf1, qf1, a, 0, 0, 0);
            uint2 pu;
            pu.x = pack2t(a[0] * SC, a[1] * SC);
            pu.y = pack2t(a[2] * SC, a[3] * SC);
            int ch = ((j0 >> 3) + (lhi >> 1)) ^ l15;
            *(uint2*)(pb + l15 * 1024 + ch * 8 + (lhi & 1) * 4) = pu;
        }
        __syncthreads();

        // ---- Phase 2: softmax1 -> cumsum -> decay -> softmax2 (normalized), in place ----
        if (hs == 0) phase2_rows<8>(pb, r0, wid, lane, g2);
        else         phase2_rows<16>(pb, r0, wid, lane, g2);
        __syncthreads();

        // ---- Phase 3: out^T = V^T . P^T via mfma(v_frag, p_frag) ----
        const int d0 = wid * 16;
        f32x4 acc = {0.f, 0.f, 0.f, 0.f};
        for (int j0 = 0; j0 < C; j0 += 32) {
            short8 av = *(const short8*)(Vb + (size_t)(d0 + l15) * NS + j0 + lhi * 8);
            short8 pw = *(const short8*)(pb + l15 * 1024 + (((((j0 >> 3) + lhi)) ^ l15) << 3));
            acc = __builtin_amdgcn_mfma_f32_16x16x32_bf16(av, pw, acc, 0, 0, 0);
        }
        {
            int d = d0 + lhi * 4;
            int s = r0 + l15;
            uint2 pu;
            pu.x = pack2t(acc[0], acc[1]);
            pu.y = pack2t(acc[2], acc[3]);
            *(uint2*)(concat + (size_t)(bq_ * NS + s) * NDM + hq * NDK + d) = pu;
        }
        __syncthreads();   // pb reused by the second half
    }
}

extern "C" void kernel_launch(void* const* d_in, const int* in_sizes, int n_in,
                              void* d_out, int out_size, void* d_ws, size_t ws_size,
                              hipStream_t stream) {
    const float* q  = (const float*)d_in[0];
    const float* k  = (const float*)d_in[1];
    const float* v  = (const float*)d_in[2];
    const float* Wq = (const float*)d_in[3];
    const float* bq = (const float*)d_in[4];
    const float* Wk = (const float*)d_in[5];
    const float* bk = (const float*)d_in[6];
    const float* Wv = (const float*)d_in[7];
    const float* bv = (const float*)d_in[8];
    const float* Wo = (const float*)d_in[9];
    const float* bo = (const float*)d_in[10];
    const float* gm = (const float*)d_in[11];

    char* w = (char*)d_ws;
    unsigned short* Qh     = (unsigned short*)(w);
    unsigned short* Kh     = (unsigned short*)(w + (size_t)8388608);
    unsigned short* Vt     = (unsigned short*)(w + (size_t)16777216);
    unsigned short* concat = (unsigned short*)(w + (size_t)25165824);

    qkv_gemm<<<dim3(256, 3), dim3(256), 0, stream>>>(q, k, v, Wq, Wk, Wv, bq, bk, bv, Qh, Kh, Vt);
    attn_kernel<<<dim3(2048), dim3(256), 0, stream>>>(Qh, Kh, Vt, gm, concat);
    wo_gemm<<<dim3(256), dim3(256), 0, stream>>>(concat, Wo, bo, (float*)d_out);
}

// Round 14
// 131.835 us; speedup vs baseline: 1.0151x; 1.0151x over previous
//
#include <hip/hip_runtime.h>
#include <hip/hip_bf16.h>
#include <math.h>

// Problem constants (fixed by setup_inputs)
#define NB   8          // batch
#define NS   1024       // seq len
#define NDM  512        // d_model
#define NH   8          // heads
#define NDK  64         // d_k
#define NM   8192       // NB*NS

typedef __attribute__((ext_vector_type(8))) short short8;
typedef __attribute__((ext_vector_type(4))) float f32x4;

__device__ __forceinline__ unsigned short f2b(float f) {
    __hip_bfloat16 h = __float2bfloat16(f);
    unsigned short u;
    __builtin_memcpy(&u, &h, 2);
    return u;
}
__device__ __forceinline__ float b2f(unsigned short u) {
    return __uint_as_float(((unsigned)u) << 16);
}
// raw transcendentals (v_exp_f32 is natively 2^x)
__device__ __forceinline__ float exp2_raw(float x) { float r; asm("v_exp_f32 %0, %1" : "=v"(r) : "v"(x)); return r; }
__device__ __forceinline__ float sqrt_raw(float x) { float r; asm("v_sqrt_f32 %0, %1" : "=v"(r) : "v"(x)); return r; }
__device__ __forceinline__ float rcp_raw(float x)  { float r; asm("v_rcp_f32 %0, %1" : "=v"(r) : "v"(x)); return r; }

// DPP helpers (cross-lane at VALU rate)
template<int CTRL, int RM>
__device__ __forceinline__ float dpp_mov0(float x) {
    int m = __builtin_amdgcn_update_dpp(0, __float_as_int(x), CTRL, RM, 0xf, true);
    return __int_as_float(m);
}
__device__ __forceinline__ float wave_incl_scan(float x) {
    x += dpp_mov0<0x111, 0xf>(x);   // row_shr:1
    x += dpp_mov0<0x112, 0xf>(x);   // row_shr:2
    x += dpp_mov0<0x114, 0xf>(x);   // row_shr:4
    x += dpp_mov0<0x118, 0xf>(x);   // row_shr:8
    x += dpp_mov0<0x142, 0xa>(x);   // row_bcast:15 -> rows 1,3
    x += dpp_mov0<0x143, 0xc>(x);   // row_bcast:31 -> rows 2,3
    return x;
}
__device__ __forceinline__ float lane63(float x) {
    return __int_as_float(__builtin_amdgcn_readlane(__float_as_int(x), 63));
}

__device__ __forceinline__ short8 pack8(float4 a, float4 b) {
    short8 r;
    r[0] = (short)f2b(a.x); r[1] = (short)f2b(a.y);
    r[2] = (short)f2b(a.z); r[3] = (short)f2b(a.w);
    r[4] = (short)f2b(b.x); r[5] = (short)f2b(b.y);
    r[6] = (short)f2b(b.z); r[7] = (short)f2b(b.w);
    return r;
}

// async 16B global -> LDS (wave-uniform dest base + lane*16; per-lane SOURCE ok)
__device__ __forceinline__ void gload16(const unsigned short* g, unsigned short* l) {
    __builtin_amdgcn_global_load_lds(
        (const __attribute__((address_space(1))) void*)g,
        (__attribute__((address_space(3))) void*)l, 16, 0, 0);
}

// Convert Wq,Wk,Wv (f32 512x512 each) to bf16 into scratch (d_out region).
__global__ __launch_bounds__(256) void cvt_w3(const float* __restrict__ Wq,
                                              const float* __restrict__ Wk,
                                              const float* __restrict__ Wv,
                                              unsigned short* __restrict__ out) {
    int idx = blockIdx.x * 256 + threadIdx.x;        // 196608 groups of 4 f32
    int m = idx >> 16;
    const float* s = (m == 0) ? Wq : ((m == 1) ? Wk : Wv);
    float4 f = *(const float4*)(s + (size_t)(idx & 65535) * 4);
    ushort4 u;
    u.x = f2b(f.x); u.y = f2b(f.y); u.z = f2b(f.z); u.w = f2b(f.w);
    *(ushort4*)(out + (size_t)idx * 4) = u;
}

// C = A @ W^T + bias.  BM=64, BN=128, BK=64.  XOR-swizzled LDS (chunk ^= row&7)
// for conflict-free b128 fragment reads; DMA path pre-swizzles the GLOBAL source
// (LDS dest stays linear — G21 both-sides rule; XOR is an involution).
// ACVT: A f32 -> convert in staging; else bf16 DMA.
// BCVT: W f32 -> convert in staging; else bf16 DMA (pre-converted weights).
// OMODE 0: out bf16 [b][h][s][d]; 1: bf16 [b][h][d][s]; 2: f32 [m][n].
template<int OMODE, bool ACVT, bool BCVT>
__device__ __forceinline__ void gemm_body64(unsigned short* As, unsigned short* Bs,
                                            const void* __restrict__ Ap,
                                            const void* __restrict__ Wp,
                                            const float* __restrict__ bias,
                                            void* __restrict__ outp) {
    const int tid = threadIdx.x, lane = tid & 63, wid = tid >> 6;
    const int l15 = lane & 15, lhi = lane >> 4;
    const int m0 = (blockIdx.x >> 2) * 64;    // 128 M-tiles
    const int n0 = (blockIdx.x & 3) * 128;    // 4 N-tiles
    const int wr = wid >> 1, wc = wid & 1;    // wave -> 32x64 output sub-tile
    const float* Af = (const float*)Ap;
    const unsigned short* Ab = (const unsigned short*)Ap;
    const float* Wf = (const float*)Wp;
    const unsigned short* Wb = (const unsigned short*)Wp;

    f32x4 acc[2][4];
#pragma unroll
    for (int i = 0; i < 2; ++i)
#pragma unroll
        for (int j = 0; j < 4; ++j) acc[i][j] = (f32x4){0.f, 0.f, 0.f, 0.f};

    for (int kk0 = 0; kk0 < NDM; kk0 += 64) {
        // ---- stage A: 64 rows x 64 k (8 KB bf16) ----
#pragma unroll
        for (int c = 0; c < 2; ++c) {
            int ci = tid + 256 * c, row = ci >> 3, ch = ci & 7;
            int sch = ch ^ (row & 7);
            if (ACVT) {
                const float* p = Af + (size_t)(m0 + row) * NDM + kk0 + ch * 8;
                *(short8*)(As + row * 64 + sch * 8) = pack8(*(const float4*)p, *(const float4*)(p + 4));
            } else {
                gload16(Ab + (size_t)(m0 + row) * NDM + kk0 + sch * 8, As + ci * 8);
            }
        }
        // ---- stage B: 128 rows x 64 k (16 KB bf16) ----
#pragma unroll
        for (int c = 0; c < 4; ++c) {
            int ci = tid + 256 * c, row = ci >> 3, ch = ci & 7;
            int sch = ch ^ (row & 7);
            if (BCVT) {
                const float* p = Wf + (size_t)(n0 + row) * NDM + kk0 + ch * 8;
                *(short8*)(Bs + row * 64 + sch * 8) = pack8(*(const float4*)p, *(const float4*)(p + 4));
            } else {
                gload16(Wb + (size_t)(n0 + row) * NDM + kk0 + sch * 8, Bs + ci * 8);
            }
        }
        __syncthreads();
        short8 af[2][2], bf[4][2];
#pragma unroll
        for (int mi = 0; mi < 2; ++mi)
#pragma unroll
            for (int kk = 0; kk < 2; ++kk) {
                int row = wr * 32 + mi * 16 + l15;
                af[mi][kk] = *(const short8*)(As + row * 64 + (((kk * 4 + lhi) ^ (l15 & 7)) << 3));
            }
#pragma unroll
        for (int ni = 0; ni < 4; ++ni)
#pragma unroll
            for (int kk = 0; kk < 2; ++kk) {
                int row = wc * 64 + ni * 16 + l15;
                bf[ni][kk] = *(const short8*)(Bs + row * 64 + (((kk * 4 + lhi) ^ (l15 & 7)) << 3));
            }
#pragma unroll
        for (int mi = 0; mi < 2; ++mi)
#pragma unroll
            for (int ni = 0; ni < 4; ++ni) {
                acc[mi][ni] = __builtin_amdgcn_mfma_f32_16x16x32_bf16(af[mi][0], bf[ni][0], acc[mi][ni], 0, 0, 0);
                acc[mi][ni] = __builtin_amdgcn_mfma_f32_16x16x32_bf16(af[mi][1], bf[ni][1], acc[mi][ni], 0, 0, 0);
            }
        __syncthreads();
    }

#pragma unroll
    for (int mi = 0; mi < 2; ++mi) {
#pragma unroll
        for (int ni = 0; ni < 4; ++ni) {
            int row0 = m0 + wr * 32 + mi * 16 + lhi * 4;
            int col  = n0 + wc * 64 + ni * 16 + l15;
            float bv = bias[col];
            if (OMODE == 0) {
                unsigned short* o = (unsigned short*)outp;
                int h = col >> 6, d = col & 63;
#pragma unroll
                for (int r = 0; r < 4; ++r) {
                    int m = row0 + r;
                    int b = m >> 10, s = m & 1023;
                    o[(size_t)(((b * NH + h) * NS) + s) * NDK + d] = f2b(acc[mi][ni][r] + bv);
                }
            } else if (OMODE == 1) {
                unsigned short* o = (unsigned short*)outp;
                int h = col >> 6, d = col & 63;
                int b = row0 >> 10, s0 = row0 & 1023;
                ushort4 u;
                u.x = f2b(acc[mi][ni][0] + bv);
                u.y = f2b(acc[mi][ni][1] + bv);
                u.z = f2b(acc[mi][ni][2] + bv);
                u.w = f2b(acc[mi][ni][3] + bv);
                *(ushort4*)(o + (size_t)((b * NH + h) * NDK + d) * NS + s0) = u;
            } else {
                float* o = (float*)outp;
#pragma unroll
                for (int r = 0; r < 4; ++r)
                    o[(size_t)(row0 + r) * NDM + col] = acc[mi][ni][r] + bv;
            }
        }
    }
}

// QKV projections: A f32 convert-staged, B = pre-converted bf16 weights via DMA.
__global__ __launch_bounds__(256, 4) void qkv_gemm(const float* __restrict__ q,
                                                   const float* __restrict__ k,
                                                   const float* __restrict__ v,
                                                   const unsigned short* __restrict__ Wqb,
                                                   const unsigned short* __restrict__ Wkb,
                                                   const unsigned short* __restrict__ Wvb,
                                                   const float* __restrict__ bq,
                                                   const float* __restrict__ bk,
                                                   const float* __restrict__ bv,
                                                   unsigned short* __restrict__ Qh,
                                                   unsigned short* __restrict__ Kh,
                                                   unsigned short* __restrict__ Vt) {
    __shared__ unsigned short As[64 * 64];
    __shared__ unsigned short Bs[128 * 64];
    const int y = blockIdx.y;
    if (y == 0)      gemm_body64<0, true, false>(As, Bs, q, Wqb, bq, Qh);
    else if (y == 1) gemm_body64<0, true, false>(As, Bs, k, Wkb, bk, Kh);
    else             gemm_body64<1, true, false>(As, Bs, v, Wvb, bv, Vt);
}

// Wo GEMM: A (concat bf16) via DMA, Wo f32 convert-staged.
__global__ __launch_bounds__(256, 4) void wo_gemm(const unsigned short* __restrict__ A,
                                                  const float* __restrict__ Wo,
                                                  const float* __restrict__ bo,
                                                  float* __restrict__ out) {
    __shared__ unsigned short As[64 * 64];
    __shared__ unsigned short Bs[128 * 64];
    gemm_body64<2, false, true>(As, Bs, A, Wo, bo, out);
}

// Phase-2 row processor: EW = cols per lane (8 for C<=512 tiles, 16 otherwise).
// EW=8: ONE b128 load/store, 8-iter loops, no per-element guards.
template<int EW>
__device__ __forceinline__ void phase2_rows(unsigned short* pb, int r0, int wid,
                                            int lane, float g2) {
    const int cb = lane * EW;
#pragma unroll
    for (int t = 0; t < 4; ++t) {
        const int rr = wid + 4 * t;
        const int i  = r0 + rr;
        unsigned short* rowp = pb + rr * 1024;
        float s[EW];
        if (EW == 8) {
            short8 raw = *(const short8*)(rowp + ((lane ^ rr) << 3));
#pragma unroll
            for (int u = 0; u < 8; ++u) s[u] = b2f((unsigned short)raw[u]);
        } else {
            short8 raw0 = *(const short8*)(rowp + (((2 * lane)     ^ rr) << 3));
            short8 raw1 = *(const short8*)(rowp + (((2 * lane + 1) ^ rr) << 3));
#pragma unroll
            for (int u = 0; u < 8; ++u) {
                s[u]     = b2f((unsigned short)raw0[u]);
                s[(EW == 16 ? 8 : 0) + u] = b2f((unsigned short)raw1[u]);
            }
        }
        // causal mask (also sanitizes stale cols beyond C: there cb+u >= C > i)
#pragma unroll
        for (int u = 0; u < EW; ++u)
            if (cb + u > i) s[u] = -1e30f;
        // softmax1 (no max): exp2 + local inclusive prefix
        float p[EW];
        float run = 0.f;
#pragma unroll
        for (int u = 0; u < EW; ++u) { run += exp2_raw(s[u]); p[u] = run; }
        const float inc      = wave_incl_scan(run);
        const float l1       = lane63(inc);
        const float invl1    = rcp_raw(l1);
        const float taillane = l1 - (inc - run);   // l1 - excl
        const float di       = (float)(i - cb);
        // decay + second softmax; masked cols: tail==0 -> te=1 -> w=0
        float l2 = 0.f;
#pragma unroll
        for (int u = 0; u < EW; ++u) {
            float tail = fmaxf(taillane - p[u], 0.f);
            float t2   = (tail * invl1) * (di - (float)u);
            float te   = fmaxf(exp2_raw(g2 * sqrt_raw(t2)), 1e-5f);
            float w    = exp2_raw(s[u] * te);
            s[u] = w;
            l2 += w;
        }
        const float l2t  = lane63(wave_incl_scan(l2));
        const float inv2 = rcp_raw(l2t);
        if (EW == 8) {
            short8 h;
#pragma unroll
            for (int u = 0; u < 8; ++u) h[u] = (short)f2b(s[u] * inv2);
            *(short8*)(rowp + ((lane ^ rr) << 3)) = h;
        } else {
            short8 h0, h1;
#pragma unroll
            for (int u = 0; u < 8; ++u) {
                h0[u] = (short)f2b(s[u] * inv2);
                h1[u] = (short)f2b(s[(EW == 16 ? 8 : 0) + u] * inv2);
            }
            *(short8*)(rowp + (((2 * lane)     ^ rr) << 3)) = h0;
            *(short8*)(rowp + (((2 * lane + 1) ^ rr) << 3)) = h1;
        }
    }
}

// Fused causal attention with distance decay.  (R12's exact kernel — best at 77.6us.)
// bf16 LDS tile [16 rows][1024 cols] = 32768 B, 4 blocks/CU.
// Block = q-tile PAIR (p, 63-p); hs=0 -> EW=8 phase-2 path.  bh in low 6 bits
// pins head to XCD bh%8 (K/V L2-resident, FETCH ~12 MB — do not perturb).
__global__ __launch_bounds__(256, 4) void attn_kernel(const unsigned short* __restrict__ Qh,
                                                      const unsigned short* __restrict__ Kh,
                                                      const unsigned short* __restrict__ Vt,
                                                      const float* __restrict__ gammas,
                                                      unsigned short* __restrict__ concat) {
    __shared__ unsigned short pb[16 * 1024];   // 32 KB bf16 tile (scores -> probs in place)
    const int bh   = blockIdx.x & 63;
    const int pair = blockIdx.x >> 6;          // 0..31
    const int tid = threadIdx.x, lane = tid & 63, wid = tid >> 6;
    const int l15 = lane & 15, lhi = lane >> 4;
    const float SC = 0.125f * 1.44269504f;     // score scale * log2(e)

    const unsigned short* Kb = Kh + (size_t)bh * NS * NDK;
    const unsigned short* Vb = Vt + (size_t)bh * NDK * NS;
    const float g  = gammas[bh & (NH - 1)];
    const float g2 = -log1pf(__expf(g)) * 1.44269504f;   // -softplus * log2(e)
    const int bq_ = bh >> 3, hq = bh & 7;

    for (int hs = 0; hs < 2; ++hs) {
        const int qt = hs ? (63 - pair) : pair;
        const int r0 = qt * 16;
        const int C  = ((r0 + 16 + 63) >> 6) << 6;   // cols computed (<=1024; <=512 for hs=0)

        // ---- Phase 1: swapped QK^T: D[k-local][q-local] = mfma(K_frag, Q_frag) ----
        const unsigned short* Qb = Qh + (size_t)(bh * NS + r0) * NDK;
        short8 qf0 = *(const short8*)(Qb + l15 * NDK + lhi * 8);
        short8 qf1 = *(const short8*)(Qb + l15 * NDK + lhi * 8 + 32);
        for (int j0 = wid * 16; j0 < C; j0 += 64) {
            const unsigned short* kp = Kb + (size_t)(j0 + l15) * NDK + lhi * 8;
            short8 kf0 = *(const short8*)kp;
            short8 kf1 = *(const short8*)(kp + 32);
            f32x4 a = {0.f, 0.f, 0.f, 0.f};
            a = __builtin_amdgcn_mfma_f32_16x16x32_bf16(kf0, qf0, a, 0, 0, 0);
            a = __builtin_amdgcn_mfma_f32_16x16x32_bf16(kf1, qf1, a, 0, 0, 0);
            ushort4 u;
            u.x = f2b(a[0] * SC);
            u.y = f2b(a[1] * SC);
            u.z = f2b(a[2] * SC);
            u.w = f2b(a[3] * SC);
            int ch = ((j0 >> 3) + (lhi >> 1)) ^ l15;
            *(ushort4*)(pb + l15 * 1024 + ch * 8 + (lhi & 1) * 4) = u;
        }
        __syncthreads();

        // ---- Phase 2: softmax1 -> cumsum -> decay -> softmax2 (normalized), in place ----
        if (hs == 0) phase2_rows<8>(pb, r0, wid, lane, g2);
        else         phase2_rows<16>(pb, r0, wid, lane, g2);
        __syncthreads();

        // ---- Phase 3: out^T = V^T . P^T via mfma(v_frag, p_frag) ----
        const int d0 = wid * 16;
        f32x4 acc = {0.f, 0.f, 0.f, 0.f};
        for (int j0 = 0; j0 < C; j0 += 32) {
            short8 av = *(const short8*)(Vb + (size_t)(d0 + l15) * NS + j0 + lhi * 8);
            short8 pw = *(const short8*)(pb + l15 * 1024 + (((((j0 >> 3) + lhi)) ^ l15) << 3));
            acc = __builtin_amdgcn_mfma_f32_16x16x32_bf16(av, pw, acc, 0, 0, 0);
        }
        {
            int d = d0 + lhi * 4;
            int s = r0 + l15;
            ushort4 u;
            u.x = f2b(acc[0]); u.y = f2b(acc[1]);
            u.z = f2b(acc[2]); u.w = f2b(acc[3]);
            *(ushort4*)(concat + (size_t)(bq_ * NS + s) * NDM + hq * NDK + d) = u;
        }
        __syncthreads();   // pb reused by the second half
    }
}

extern "C" void kernel_launch(void* const* d_in, const int* in_sizes, int n_in,
                              void* d_out, int out_size, void* d_ws, size_t ws_size,
                              hipStream_t stream) {
    const float* q  = (const float*)d_in[0];
    const float* k  = (const float*)d_in[1];
    const float* v  = (const float*)d_in[2];
    const float* Wq = (const float*)d_in[3];
    const float* bq = (const float*)d_in[4];
    const float* Wk = (const float*)d_in[5];
    const float* bk = (const float*)d_in[6];
    const float* Wv = (const float*)d_in[7];
    const float* bv = (const float*)d_in[8];
    const float* Wo = (const float*)d_in[9];
    const float* bo = (const float*)d_in[10];
    const float* gm = (const float*)d_in[11];

    char* w = (char*)d_ws;
    unsigned short* Qh     = (unsigned short*)(w);
    unsigned short* Kh     = (unsigned short*)(w + (size_t)8388608);
    unsigned short* Vt     = (unsigned short*)(w + (size_t)16777216);
    unsigned short* concat = (unsigned short*)(w + (size_t)25165824);

    // d_out (16.7 MB) used as scratch for bf16 Wq/Wk/Wv until wo_gemm overwrites it
    // (qkv_gemm finishes reading them before wo_gemm launches; stream-ordered).
    unsigned short* Wqb = (unsigned short*)d_out;
    unsigned short* Wkb = Wqb + 262144;
    unsigned short* Wvb = Wqb + 524288;

    cvt_w3<<<dim3(768), dim3(256), 0, stream>>>(Wq, Wk, Wv, Wqb);
    qkv_gemm<<<dim3(512, 3), dim3(256), 0, stream>>>(q, k, v, Wqb, Wkb, Wvb, bq, bk, bv, Qh, Kh, Vt);
    attn_kernel<<<dim3(2048), dim3(256), 0, stream>>>(Qh, Kh, Vt, gm, concat);
    wo_gemm<<<dim3(512), dim3(256), 0, stream>>>(concat, Wo, bo, (float*)d_out);
}

// Round 15
// 123.354 us; speedup vs baseline: 1.0848x; 1.0688x over previous
//
#include <hip/hip_runtime.h>
#include <hip/hip_bf16.h>
#include <math.h>

// Problem constants (fixed by setup_inputs)
#define NB   8          // batch
#define NS   1024       // seq len
#define NDM  512        // d_model
#define NH   8          // heads
#define NDK  64         // d_k
#define NM   8192       // NB*NS

typedef __attribute__((ext_vector_type(8))) short short8;
typedef __attribute__((ext_vector_type(4))) float f32x4;

__device__ __forceinline__ unsigned short f2b(float f) {
    __hip_bfloat16 h = __float2bfloat16(f);
    unsigned short u;
    __builtin_memcpy(&u, &h, 2);
    return u;
}
__device__ __forceinline__ float b2f(unsigned short u) {
    return __uint_as_float(((unsigned)u) << 16);
}
// raw transcendentals (v_exp_f32 is natively 2^x)
__device__ __forceinline__ float exp2_raw(float x) { float r; asm("v_exp_f32 %0, %1" : "=v"(r) : "v"(x)); return r; }
__device__ __forceinline__ float sqrt_raw(float x) { float r; asm("v_sqrt_f32 %0, %1" : "=v"(r) : "v"(x)); return r; }
__device__ __forceinline__ float rcp_raw(float x)  { float r; asm("v_rcp_f32 %0, %1" : "=v"(r) : "v"(x)); return r; }

// DPP helpers (cross-lane at VALU rate)
template<int CTRL, int RM>
__device__ __forceinline__ float dpp_mov0(float x) {
    int m = __builtin_amdgcn_update_dpp(0, __float_as_int(x), CTRL, RM, 0xf, true);
    return __int_as_float(m);
}
__device__ __forceinline__ float wave_incl_scan(float x) {
    x += dpp_mov0<0x111, 0xf>(x);   // row_shr:1
    x += dpp_mov0<0x112, 0xf>(x);   // row_shr:2
    x += dpp_mov0<0x114, 0xf>(x);   // row_shr:4
    x += dpp_mov0<0x118, 0xf>(x);   // row_shr:8
    x += dpp_mov0<0x142, 0xa>(x);   // row_bcast:15 -> rows 1,3
    x += dpp_mov0<0x143, 0xc>(x);   // row_bcast:31 -> rows 2,3
    return x;
}
__device__ __forceinline__ float lane63(float x) {
    return __int_as_float(__builtin_amdgcn_readlane(__float_as_int(x), 63));
}

__device__ __forceinline__ short8 pack8(float4 a, float4 b) {
    short8 r;
    r[0] = (short)f2b(a.x); r[1] = (short)f2b(a.y);
    r[2] = (short)f2b(a.z); r[3] = (short)f2b(a.w);
    r[4] = (short)f2b(b.x); r[5] = (short)f2b(b.y);
    r[6] = (short)f2b(b.z); r[7] = (short)f2b(b.w);
    return r;
}

// async 16B global -> LDS (wave-uniform dest base + lane*16; per-lane SOURCE ok)
__device__ __forceinline__ void gload16(const unsigned short* g, unsigned short* l) {
    __builtin_amdgcn_global_load_lds(
        (const __attribute__((address_space(1))) void*)g,
        (__attribute__((address_space(3))) void*)l, 16, 0, 0);
}

// C = A @ W^T + bias.  BM=64, BN=128, BK=64.  XOR-swizzled LDS (chunk ^= row&7).
// XCD-LOCAL A REUSE: m in LOW bits of blockIdx, n in HIGH bits -> the 4 N-tiles
// of one M-strip have bids m, 128+m, 256+m, 384+m == m (mod 8) -> SAME XCD ->
// A-strip fetched from HBM once, re-reads hit that XCD's L2 (16 strips x 128KB
// = 2MB < 4MB).  Old layout (n in low bits) spread them over 4 XCDs: A traffic
// 4x50MB = 200MB, qkv at ~6 TB/s = HBM-bound.
// ACVT: A f32 -> convert in staging; else bf16 DMA (pre-swizzled global source).
// BCVT: W f32 -> convert in staging; else bf16 DMA.
// OMODE 0: out bf16 [b][h][s][d]; 1: bf16 [b][h][d][s]; 2: f32 [m][n].
template<int OMODE, bool ACVT, bool BCVT>
__device__ __forceinline__ void gemm_body64(unsigned short* As, unsigned short* Bs,
                                            const void* __restrict__ Ap,
                                            const void* __restrict__ Wp,
                                            const float* __restrict__ bias,
                                            void* __restrict__ outp) {
    const int tid = threadIdx.x, lane = tid & 63, wid = tid >> 6;
    const int l15 = lane & 15, lhi = lane >> 4;
    const int m0 = (blockIdx.x & 127) * 64;   // 128 M-strips (LOW bits -> XCD-pinned)
    const int n0 = (blockIdx.x >> 7) * 128;   // 4 N-tiles   (HIGH bits)
    const int wr = wid >> 1, wc = wid & 1;    // wave -> 32x64 output sub-tile
    const float* Af = (const float*)Ap;
    const unsigned short* Ab = (const unsigned short*)Ap;
    const float* Wf = (const float*)Wp;
    const unsigned short* Wb = (const unsigned short*)Wp;

    f32x4 acc[2][4];
#pragma unroll
    for (int i = 0; i < 2; ++i)
#pragma unroll
        for (int j = 0; j < 4; ++j) acc[i][j] = (f32x4){0.f, 0.f, 0.f, 0.f};

    for (int kk0 = 0; kk0 < NDM; kk0 += 64) {
        // ---- stage A: 64 rows x 64 k (8 KB bf16) ----
#pragma unroll
        for (int c = 0; c < 2; ++c) {
            int ci = tid + 256 * c, row = ci >> 3, ch = ci & 7;
            int sch = ch ^ (row & 7);
            if (ACVT) {
                const float* p = Af + (size_t)(m0 + row) * NDM + kk0 + ch * 8;
                *(short8*)(As + row * 64 + sch * 8) = pack8(*(const float4*)p, *(const float4*)(p + 4));
            } else {
                gload16(Ab + (size_t)(m0 + row) * NDM + kk0 + sch * 8, As + ci * 8);
            }
        }
        // ---- stage B: 128 rows x 64 k (16 KB bf16) ----
#pragma unroll
        for (int c = 0; c < 4; ++c) {
            int ci = tid + 256 * c, row = ci >> 3, ch = ci & 7;
            int sch = ch ^ (row & 7);
            if (BCVT) {
                const float* p = Wf + (size_t)(n0 + row) * NDM + kk0 + ch * 8;
                *(short8*)(Bs + row * 64 + sch * 8) = pack8(*(const float4*)p, *(const float4*)(p + 4));
            } else {
                gload16(Wb + (size_t)(n0 + row) * NDM + kk0 + sch * 8, Bs + ci * 8);
            }
        }
        __syncthreads();
        short8 af[2][2], bf[4][2];
#pragma unroll
        for (int mi = 0; mi < 2; ++mi)
#pragma unroll
            for (int kk = 0; kk < 2; ++kk) {
                int row = wr * 32 + mi * 16 + l15;
                af[mi][kk] = *(const short8*)(As + row * 64 + (((kk * 4 + lhi) ^ (l15 & 7)) << 3));
            }
#pragma unroll
        for (int ni = 0; ni < 4; ++ni)
#pragma unroll
            for (int kk = 0; kk < 2; ++kk) {
                int row = wc * 64 + ni * 16 + l15;
                bf[ni][kk] = *(const short8*)(Bs + row * 64 + (((kk * 4 + lhi) ^ (l15 & 7)) << 3));
            }
#pragma unroll
        for (int mi = 0; mi < 2; ++mi)
#pragma unroll
            for (int ni = 0; ni < 4; ++ni) {
                acc[mi][ni] = __builtin_amdgcn_mfma_f32_16x16x32_bf16(af[mi][0], bf[ni][0], acc[mi][ni], 0, 0, 0);
                acc[mi][ni] = __builtin_amdgcn_mfma_f32_16x16x32_bf16(af[mi][1], bf[ni][1], acc[mi][ni], 0, 0, 0);
            }
        __syncthreads();
    }

#pragma unroll
    for (int mi = 0; mi < 2; ++mi) {
#pragma unroll
        for (int ni = 0; ni < 4; ++ni) {
            int row0 = m0 + wr * 32 + mi * 16 + lhi * 4;
            int col  = n0 + wc * 64 + ni * 16 + l15;
            float bv = bias[col];
            if (OMODE == 0) {
                unsigned short* o = (unsigned short*)outp;
                int h = col >> 6, d = col & 63;
#pragma unroll
                for (int r = 0; r < 4; ++r) {
                    int m = row0 + r;
                    int b = m >> 10, s = m & 1023;
                    o[(size_t)(((b * NH + h) * NS) + s) * NDK + d] = f2b(acc[mi][ni][r] + bv);
                }
            } else if (OMODE == 1) {
                unsigned short* o = (unsigned short*)outp;
                int h = col >> 6, d = col & 63;
                int b = row0 >> 10, s0 = row0 & 1023;
                ushort4 u;
                u.x = f2b(acc[mi][ni][0] + bv);
                u.y = f2b(acc[mi][ni][1] + bv);
                u.z = f2b(acc[mi][ni][2] + bv);
                u.w = f2b(acc[mi][ni][3] + bv);
                *(ushort4*)(o + (size_t)((b * NH + h) * NDK + d) * NS + s0) = u;
            } else {
                float* o = (float*)outp;
#pragma unroll
                for (int r = 0; r < 4; ++r)
                    o[(size_t)(row0 + r) * NDM + col] = acc[mi][ni][r] + bv;
            }
        }
    }
}

// QKV projections: A f32 + W f32, both convert-in-staging (R12 config).
__global__ __launch_bounds__(256, 4) void qkv_gemm(const float* __restrict__ q,
                                                   const float* __restrict__ k,
                                                   const float* __restrict__ v,
                                                   const float* __restrict__ Wq,
                                                   const float* __restrict__ Wk,
                                                   const float* __restrict__ Wv,
                                                   const float* __restrict__ bq,
                                                   const float* __restrict__ bk,
                                                   const float* __restrict__ bv,
                                                   unsigned short* __restrict__ Qh,
                                                   unsigned short* __restrict__ Kh,
                                                   unsigned short* __restrict__ Vt) {
    __shared__ unsigned short As[64 * 64];
    __shared__ unsigned short Bs[128 * 64];
    const int y = blockIdx.y;
    if (y == 0)      gemm_body64<0, true, true>(As, Bs, q, Wq, bq, Qh);
    else if (y == 1) gemm_body64<0, true, true>(As, Bs, k, Wk, bk, Kh);
    else             gemm_body64<1, true, true>(As, Bs, v, Wv, bv, Vt);
}

// Wo GEMM: A (concat bf16) via DMA w/ pre-swizzled source, Wo f32 convert-staged.
__global__ __launch_bounds__(256, 4) void wo_gemm(const unsigned short* __restrict__ A,
                                                  const float* __restrict__ Wo,
                                                  const float* __restrict__ bo,
                                                  float* __restrict__ out) {
    __shared__ unsigned short As[64 * 64];
    __shared__ unsigned short Bs[128 * 64];
    gemm_body64<2, false, true>(As, Bs, A, Wo, bo, out);
}

// Phase-2 row processor: EW = cols per lane (8 for C<=512 tiles, 16 otherwise).
template<int EW>
__device__ __forceinline__ void phase2_rows(unsigned short* pb, int r0, int wid,
                                            int lane, float g2) {
    const int cb = lane * EW;
#pragma unroll
    for (int t = 0; t < 4; ++t) {
        const int rr = wid + 4 * t;
        const int i  = r0 + rr;
        unsigned short* rowp = pb + rr * 1024;
        float s[EW];
        if (EW == 8) {
            short8 raw = *(const short8*)(rowp + ((lane ^ rr) << 3));
#pragma unroll
            for (int u = 0; u < 8; ++u) s[u] = b2f((unsigned short)raw[u]);
        } else {
            short8 raw0 = *(const short8*)(rowp + (((2 * lane)     ^ rr) << 3));
            short8 raw1 = *(const short8*)(rowp + (((2 * lane + 1) ^ rr) << 3));
#pragma unroll
            for (int u = 0; u < 8; ++u) {
                s[u]     = b2f((unsigned short)raw0[u]);
                s[(EW == 16 ? 8 : 0) + u] = b2f((unsigned short)raw1[u]);
            }
        }
        // causal mask (also sanitizes stale cols beyond C: there cb+u >= C > i)
#pragma unroll
        for (int u = 0; u < EW; ++u)
            if (cb + u > i) s[u] = -1e30f;
        // softmax1 (no max): exp2 + local inclusive prefix
        float p[EW];
        float run = 0.f;
#pragma unroll
        for (int u = 0; u < EW; ++u) { run += exp2_raw(s[u]); p[u] = run; }
        const float inc      = wave_incl_scan(run);
        const float l1       = lane63(inc);
        const float invl1    = rcp_raw(l1);
        const float taillane = l1 - (inc - run);   // l1 - excl
        const float di       = (float)(i - cb);
        // decay + second softmax; masked cols: tail==0 -> te=1 -> w=0
        float l2 = 0.f;
#pragma unroll
        for (int u = 0; u < EW; ++u) {
            float tail = fmaxf(taillane - p[u], 0.f);
            float t2   = (tail * invl1) * (di - (float)u);
            float te   = fmaxf(exp2_raw(g2 * sqrt_raw(t2)), 1e-5f);
            float w    = exp2_raw(s[u] * te);
            s[u] = w;
            l2 += w;
        }
        const float l2t  = lane63(wave_incl_scan(l2));
        const float inv2 = rcp_raw(l2t);
        if (EW == 8) {
            short8 h;
#pragma unroll
            for (int u = 0; u < 8; ++u) h[u] = (short)f2b(s[u] * inv2);
            *(short8*)(rowp + ((lane ^ rr) << 3)) = h;
        } else {
            short8 h0, h1;
#pragma unroll
            for (int u = 0; u < 8; ++u) {
                h0[u] = (short)f2b(s[u] * inv2);
                h1[u] = (short)f2b(s[(EW == 16 ? 8 : 0) + u] * inv2);
            }
            *(short8*)(rowp + (((2 * lane)     ^ rr) << 3)) = h0;
            *(short8*)(rowp + (((2 * lane + 1) ^ rr) << 3)) = h1;
        }
    }
}

// Fused causal attention with distance decay.  (R12's exact kernel — 77.6us.)
// bf16 LDS tile [16 rows][1024 cols] = 32768 B, 4 blocks/CU.
// Block = q-tile PAIR (p, 63-p); hs=0 -> EW=8 phase-2 path.  bh in low 6 bits
// pins head to XCD bh%8 (K/V L2-resident, FETCH ~12 MB — do not perturb).
__global__ __launch_bounds__(256, 4) void attn_kernel(const unsigned short* __restrict__ Qh,
                                                      const unsigned short* __restrict__ Kh,
                                                      const unsigned short* __restrict__ Vt,
                                                      const float* __restrict__ gammas,
                                                      unsigned short* __restrict__ concat) {
    __shared__ unsigned short pb[16 * 1024];   // 32 KB bf16 tile (scores -> probs in place)
    const int bh   = blockIdx.x & 63;
    const int pair = blockIdx.x >> 6;          // 0..31
    const int tid = threadIdx.x, lane = tid & 63, wid = tid >> 6;
    const int l15 = lane & 15, lhi = lane >> 4;
    const float SC = 0.125f * 1.44269504f;     // score scale * log2(e)

    const unsigned short* Kb = Kh + (size_t)bh * NS * NDK;
    const unsigned short* Vb = Vt + (size_t)bh * NDK * NS;
    const float g  = gammas[bh & (NH - 1)];
    const float g2 = -log1pf(__expf(g)) * 1.44269504f;   // -softplus * log2(e)
    const int bq_ = bh >> 3, hq = bh & 7;

    for (int hs = 0; hs < 2; ++hs) {
        const int qt = hs ? (63 - pair) : pair;
        const int r0 = qt * 16;
        const int C  = ((r0 + 16 + 63) >> 6) << 6;   // cols computed (<=1024; <=512 for hs=0)

        // ---- Phase 1: swapped QK^T: D[k-local][q-local] = mfma(K_frag, Q_frag) ----
        const unsigned short* Qb = Qh + (size_t)(bh * NS + r0) * NDK;
        short8 qf0 = *(const short8*)(Qb + l15 * NDK + lhi * 8);
        short8 qf1 = *(const short8*)(Qb + l15 * NDK + lhi * 8 + 32);
        for (int j0 = wid * 16; j0 < C; j0 += 64) {
            const unsigned short* kp = Kb + (size_t)(j0 + l15) * NDK + lhi * 8;
            short8 kf0 = *(const short8*)kp;
            short8 kf1 = *(const short8*)(kp + 32);
            f32x4 a = {0.f, 0.f, 0.f, 0.f};
            a = __builtin_amdgcn_mfma_f32_16x16x32_bf16(kf0, qf0, a, 0, 0, 0);
            a = __builtin_amdgcn_mfma_f32_16x16x32_bf16(kf1, qf1, a, 0, 0, 0);
            ushort4 u;
            u.x = f2b(a[0] * SC);
            u.y = f2b(a[1] * SC);
            u.z = f2b(a[2] * SC);
            u.w = f2b(a[3] * SC);
            int ch = ((j0 >> 3) + (lhi >> 1)) ^ l15;
            *(ushort4*)(pb + l15 * 1024 + ch * 8 + (lhi & 1) * 4) = u;
        }
        __syncthreads();

        // ---- Phase 2: softmax1 -> cumsum -> decay -> softmax2 (normalized), in place ----
        if (hs == 0) phase2_rows<8>(pb, r0, wid, lane, g2);
        else         phase2_rows<16>(pb, r0, wid, lane, g2);
        __syncthreads();

        // ---- Phase 3: out^T = V^T . P^T via mfma(v_frag, p_frag) ----
        const int d0 = wid * 16;
        f32x4 acc = {0.f, 0.f, 0.f, 0.f};
        for (int j0 = 0; j0 < C; j0 += 32) {
            short8 av = *(const short8*)(Vb + (size_t)(d0 + l15) * NS + j0 + lhi * 8);
            short8 pw = *(const short8*)(pb + l15 * 1024 + (((((j0 >> 3) + lhi)) ^ l15) << 3));
            acc = __builtin_amdgcn_mfma_f32_16x16x32_bf16(av, pw, acc, 0, 0, 0);
        }
        {
            int d = d0 + lhi * 4;
            int s = r0 + l15;
            ushort4 u;
            u.x = f2b(acc[0]); u.y = f2b(acc[1]);
            u.z = f2b(acc[2]); u.w = f2b(acc[3]);
            *(ushort4*)(concat + (size_t)(bq_ * NS + s) * NDM + hq * NDK + d) = u;
        }
        __syncthreads();   // pb reused by the second half
    }
}

extern "C" void kernel_launch(void* const* d_in, const int* in_sizes, int n_in,
                              void* d_out, int out_size, void* d_ws, size_t ws_size,
                              hipStream_t stream) {
    const float* q  = (const float*)d_in[0];
    const float* k  = (const float*)d_in[1];
    const float* v  = (const float*)d_in[2];
    const float* Wq = (const float*)d_in[3];
    const float* bq = (const float*)d_in[4];
    const float* Wk = (const float*)d_in[5];
    const float* bk = (const float*)d_in[6];
    const float* Wv = (const float*)d_in[7];
    const float* bv = (const float*)d_in[8];
    const float* Wo = (const float*)d_in[9];
    const float* bo = (const float*)d_in[10];
    const float* gm = (const float*)d_in[11];

    char* w = (char*)d_ws;
    unsigned short* Qh     = (unsigned short*)(w);
    unsigned short* Kh     = (unsigned short*)(w + (size_t)8388608);
    unsigned short* Vt     = (unsigned short*)(w + (size_t)16777216);
    unsigned short* concat = (unsigned short*)(w + (size_t)25165824);

    qkv_gemm<<<dim3(512, 3), dim3(256), 0, stream>>>(q, k, v, Wq, Wk, Wv, bq, bk, bv, Qh, Kh, Vt);
    attn_kernel<<<dim3(2048), dim3(256), 0, stream>>>(Qh, Kh, Vt, gm, concat);
    wo_gemm<<<dim3(512), dim3(256), 0, stream>>>(concat, Wo, bo, (float*)d_out);
}